// Round 12
// baseline (961.034 us; speedup 1.0000x reference)
//
#include <hip/hip_runtime.h>
#include <math.h>

typedef _Float16 h16;
typedef h16 half8v __attribute__((ext_vector_type(8)));

#define HH 512
#define WW 512
#define BB 8
#define NPIX (HH*WW)        // 262144
#define NTOT (BB*NPIX)      // 2097152
#define ITER 50

#define TX 64               // tile cols
#define TILE_ROWS 64        // tile rows = 32 ty * 2 rows/thread

#define BLK_PER_BATCH 64    // tiles per batch; 512 blocks total
#define SLOTF 8             // floats per partials slot (6 sums, pad, tag)
#define PART_PAR_STRIDE (BB*BLK_PER_BATCH*SLOTF)   // one parity buffer

// Gaussian 5x5 (sigma=5)
constexpr double W0d = 0.92311634638663587;  // exp(-0.08)
constexpr double W1d = 0.98019867330675525;  // exp(-0.02)
constexpr double SUM1D = 1.0 + 2.0*(W0d + W1d);
constexpr float  INV_NORM = (float)(1.0/(SUM1D*SUM1D + 1e-15));
constexpr float  W0f = (float)W0d;
constexpr float  W1f = (float)W1d;
constexpr float  S1f = (float)SUM1D;

// ---- agent-scope (device-coherent, L2-bypassing) access helpers ----
__device__ __forceinline__ unsigned long long ald64(const void* p) {
    return __hip_atomic_load((unsigned long long*)p, __ATOMIC_RELAXED, __HIP_MEMORY_SCOPE_AGENT);
}
__device__ __forceinline__ unsigned ald32(const void* p) {
    return __hip_atomic_load((unsigned*)p, __ATOMIC_RELAXED, __HIP_MEMORY_SCOPE_AGENT);
}
__device__ __forceinline__ void ast64(void* p, unsigned long long v) {
    __hip_atomic_store((unsigned long long*)p, v, __ATOMIC_RELAXED, __HIP_MEMORY_SCOPE_AGENT);
}
__device__ __forceinline__ void ast32(void* p, unsigned v) {
    __hip_atomic_store((unsigned*)p, v, __ATOMIC_RELAXED, __HIP_MEMORY_SCOPE_AGENT);
}
union H8U  { half8v h; unsigned long long u[2]; unsigned w[4]; };
union U32H2 { unsigned u; h16 h[2]; };
union U64F2 { unsigned long long u; float f[2]; };

__device__ __forceinline__ float fast_sigmoid(float x) {
    const float e = __expf(-x);
    return __builtin_amdgcn_rcpf(1.0f + e);
}

__device__ __forceinline__ float edge1d(int v) {
    float r = S1f;
    if (v == 0 || v == HH - 1) r = S1f - W0f - W1f;
    else if (v == 1 || v == HH - 2) r = S1f - W0f;
    return r;
}

// Block reduce of 6 floats -> agent-store slot (6 sums), waitcnt, then tag.
__device__ __forceinline__ void reduce6_store_tagged(float v[6], float* dst8, float tag) {
    #pragma unroll
    for (int kk = 0; kk < 6; kk++) {
        float x = v[kk];
        #pragma unroll
        for (int off = 32; off > 0; off >>= 1) x += __shfl_down(x, off, 64);
        v[kk] = x;
    }
    __shared__ float sm[4][6];
    const int lane = threadIdx.x & 63;
    const int wv   = threadIdx.x >> 6;
    if (lane == 0) {
        #pragma unroll
        for (int kk = 0; kk < 6; kk++) sm[wv][kk] = v[kk];
    }
    __syncthreads();
    if (threadIdx.x == 0) {
        float tt[6];
        #pragma unroll
        for (int kk = 0; kk < 6; kk++) tt[kk] = sm[0][kk] + sm[1][kk] + sm[2][kk] + sm[3][kk];
        U64F2 w0, w1, w2;
        w0.f[0] = tt[0]; w0.f[1] = tt[1];
        w1.f[0] = tt[2]; w1.f[1] = tt[3];
        w2.f[0] = tt[4]; w2.f[1] = tt[5];
        ast64(dst8,     w0.u);
        ast64(dst8 + 2, w1.u);
        ast64(dst8 + 4, w2.u);
        asm volatile("s_waitcnt vmcnt(0)" ::: "memory");
        ast32(dst8 + 7, __float_as_uint(tag));
    }
}

__device__ __forceinline__ void evalF(float uc, float ud, float ur, float qv,
                                      float dx, float dy,
                                      float cossin, float bsin, float asin_,
                                      float& a, float& bv, float& qn) {
    float Tx = -dx * cossin + dy * bsin;
    float Ty =  dy * cossin - dx * asin_;
    const float rn = __builtin_amdgcn_rsqf(Tx * Tx + Ty * Ty + 1e-20f);
    Tx *= rn; Ty *= rn;
    qn = qv - ((ud - uc) * Tx + (ur - uc) * Ty);
    a  = Tx * qn;
    bv = Ty * qn;
}

// u0 = sigmoid(o) (fp16-rounded); q0 = 0; o -> fp16. Partials(u0) tag=1 ->
// parity-1; zero parity-0 tag slot (workspace poison / graph-replay stale).
__global__ __launch_bounds__(256) void init_kernel(const float* __restrict__ o,
                                                   h16* __restrict__ u,
                                                   h16* __restrict__ q,
                                                   h16* __restrict__ oh,
                                                   float* __restrict__ parts) {
    const int b     = blockIdx.x & 7;
    const int chunk = blockIdx.x >> 3;                  // 0..63
    const int within = chunk * 4096 + threadIdx.x * 16;
    const int pix = b * NPIX + within;
    const int i = within >> 9;
    const int j = within & (WW - 1);

    if (threadIdx.x == 0) {
        float* slot0 = parts + ((size_t)b * BLK_PER_BATCH + chunk) * SLOTF;
        ast32(slot0 + 7, __float_as_uint(0.0f));
    }

    float of[16];
    #pragma unroll
    for (int s = 0; s < 4; s++) {
        const float4 ov = *(const float4*)(o + pix + 4 * s);
        of[4*s+0] = ov.x; of[4*s+1] = ov.y; of[4*s+2] = ov.z; of[4*s+3] = ov.w;
    }

    half8v oh8[2], uh8[2], qz8[2];
    float urf[16];
    #pragma unroll
    for (int kk = 0; kk < 16; kk++) {
        oh8[kk >> 3][kk & 7] = (h16)of[kk];
        uh8[kk >> 3][kk & 7] = (h16)fast_sigmoid(of[kk]);
        urf[kk] = (float)uh8[kk >> 3][kk & 7];
        qz8[kk >> 3][kk & 7] = (h16)0.f;
    }
    *(half8v*)(u + pix)      = uh8[0];
    *(half8v*)(u + pix + 8)  = uh8[1];
    *(half8v*)(q + pix)      = qz8[0];
    *(half8v*)(q + pix + 8)  = qz8[1];
    *(half8v*)(oh + pix)     = oh8[0];
    *(half8v*)(oh + pix + 8) = oh8[1];
    asm volatile("s_waitcnt vmcnt(0)" ::: "memory");   // state durable before tag

    const float x = (float)(i + 1);
    float s0 = 0.f, sy = 0.f, syy = 0.f;
    #pragma unroll
    for (int kk = 0; kk < 16; kk++) {
        const float y = (float)(j + 1 + kk);
        s0 += urf[kk]; sy += urf[kk] * y; syy += urf[kk] * y * y;
    }
    float v[6] = {s0, x * s0, sy, x * sy, x * x * s0, syy};
    float* dst = parts + (size_t)1 * PART_PAR_STRIDE
                       + ((size_t)b * BLK_PER_BATCH + chunk) * SLOTF;
    reduce6_store_tagged(v, dst, 1.0f);
}

// Persistent kernel, NORMAL launch (R9/R10's hipLaunchCooperativeKernel was
// silently dropped under graph capture -> out stayed zeroed, absmax 4.09).
// Co-residency by capacity: 512 blocks = 2 blocks/CU on 256 CUs; VGPR <= 168
// gives >= 2 blocks/CU, so all blocks resident at dispatch; bounded poll guard
// makes any violation fail-visible, not hang. 8 independent 64-block barriers.
__global__ __launch_bounds__(256) void persist_kernel(const h16* __restrict__ ohh,
                                                      h16* __restrict__ u0,
                                                      h16* __restrict__ u1,
                                                      h16* __restrict__ q0,
                                                      h16* __restrict__ q1,
                                                      float* __restrict__ parts,
                                                      float* __restrict__ out) {
    const int b    = blockIdx.x & 7;
    const int tile = blockIdx.x >> 3;          // 0..63
    const int j0 = (tile & 7) * TX;
    const int i0 = (tile >> 3) * TILE_ROWS;

    const int lin  = threadIdx.x;
    const int lane = lin & 63;
    const int tx = lin & 7;
    const int ty = lin >> 3;                   // 0..31
    const int ia = i0 + 2 * ty;
    const int jb = j0 + 8 * tx;
    const int loffA = ia * WW + jb;
    const int loffB = loffA + WW;
    const size_t goffA = (size_t)b * NPIX + loffA;
    const size_t goffB = goffA + WW;

    const bool lok = (jb > 0);
    const bool rok = (jb + 8 < WW);
    const bool ltx = (tx > 0);
    const bool rtx = (tx < 7);

    const half8v oA8 = *(const half8v*)(ohh + goffA);
    const half8v oB8 = *(const half8v*)(ohh + goffB);
    const float RiA = edge1d(ia);
    const float RiB = edge1d(ia + 1);
    const float xA = (float)(ia + 1);
    const float xB = (float)(ia + 2);

    for (int m = 0; m < ITER; m++) {
        const h16* ua = (m & 1) ? u1 : u0;
        const h16* qa = (m & 1) ? q1 : q0;
        h16* ub = (m & 1) ? u0 : u1;
        h16* qb = (m & 1) ? q0 : q1;
        const h16* ubase = ua + (size_t)b * NPIX;
        const h16* qbase = qa + (size_t)b * NPIX;

        // ---- barrier: poll this batch's 64 tags (one slot per lane) ----
        const float* slotB = parts + (size_t)((m + 1) & 1) * PART_PAR_STRIDE
                                   + (size_t)b * BLK_PER_BATCH * SLOTF;
        const float target = (float)(m + 1);
        {
            int guard = 0;
            for (;;) {
                const float tg = __uint_as_float(ald32(slotB + lane * SLOTF + 7));
                if (__all(tg >= target)) break;
                if (++guard > (1 << 24)) break;   // fail-visible (slow), not hang
                __builtin_amdgcn_s_sleep(2);
            }
        }
        asm volatile("" ::: "memory");   // pin subsequent loads after the poll

        float v6[6];
        {
            U64F2 a0, a1, a2;
            const float* sp = slotB + lane * SLOTF;
            a0.u = ald64(sp);     a1.u = ald64(sp + 2); a2.u = ald64(sp + 4);
            v6[0] = a0.f[0]; v6[1] = a0.f[1]; v6[2] = a1.f[0];
            v6[3] = a1.f[1]; v6[4] = a2.f[0]; v6[5] = a2.f[1];
        }
        #pragma unroll
        for (int mask = 1; mask < 64; mask <<= 1) {
            #pragma unroll
            for (int c = 0; c < 6; c++) v6[c] += __shfl_xor(v6[c], mask, 64);
        }
        const double sS  = (double)v6[0];
        const double inv = 1.0 / sS;
        const double cxd = (double)v6[1] * inv;
        const double cyd = (double)v6[2] * inv;
        const float cxf    = (float)cxd;
        const float cyf    = (float)cyd;
        const float cossin = (float)((double)v6[3] * inv - cxd * cyd);
        const float bsin   = (float)((double)v6[4] * inv - cxd * cxd);
        const float asin_  = (float)((double)v6[5] * inv - cyd * cyd);

        // ---- u window rows ia-2..ia+3 (agent loads); halos via shfl ----
        H8U uM[6];
        unsigned uLbw[6], uRbw[6];
        #pragma unroll
        for (int r = 0; r < 6; r++) {
            const int ii = ia - 2 + r;
            const bool rowok = (ii >= 0 && ii < HH);
            H8U mrow; mrow.u[0] = 0ull; mrow.u[1] = 0ull;
            unsigned lw = 0u, rw = 0u;
            if (rowok) {
                const h16* rowp = ubase + ii * WW;
                mrow.u[0] = ald64(rowp + jb);
                mrow.u[1] = ald64(rowp + jb + 4);
                if (!ltx && lok) lw = ald32(rowp + jb - 2);
                if (!rtx && rok) rw = ald32(rowp + jb + 8);
            }
            uM[r] = mrow; uLbw[r] = lw; uRbw[r] = rw;
        }
        H8U qcA, qcB, qu;
        qcA.u[0] = ald64(qbase + loffA); qcA.u[1] = ald64(qbase + loffA + 4);
        qcB.u[0] = ald64(qbase + loffB); qcB.u[1] = ald64(qbase + loffB + 4);
        {
            const int uoff = (ia > 0) ? loffA - WW : loffA;
            qu.u[0] = ald64(qbase + uoff); qu.u[1] = ald64(qbase + uoff + 4);
        }
        h16 qlA_g = (h16)0.f, qlB_g = (h16)0.f;
        if (!ltx && lok) {
            U32H2 ta, tb;
            ta.u = ald32(qbase + loffA - 2);
            tb.u = ald32(qbase + loffB - 2);
            qlA_g = ta.h[1]; qlB_g = tb.h[1];
        }

        unsigned uLw[6], uRw[6];
        #pragma unroll
        for (int r = 0; r < 6; r++) {
            const unsigned w3 = uM[r].w[3];
            const unsigned w0 = uM[r].w[0];
            const unsigned fromL = (unsigned)__shfl((int)w3, lane - 1, 64);
            const unsigned fromR = (unsigned)__shfl((int)w0, lane + 1, 64);
            uLw[r] = ltx ? fromL : uLbw[r];
            uRw[r] = rtx ? fromR : uRbw[r];
        }
        h16 qlAh, qlBh;
        {
            U32H2 ca, cb;
            ca.u = (unsigned)__shfl((int)qcA.w[3], lane - 1, 64);
            cb.u = (unsigned)__shfl((int)qcB.w[3], lane - 1, 64);
            qlAh = ltx ? ca.h[1] : qlA_g;
            qlBh = ltx ? cb.h[1] : qlB_g;
        }

        // ---- streaming v-pass; keep rows 1..4 cols 1..10 ----
        float vsA[12], vsB[12];
        float Ue[4][10];
        constexpr float wAr[6] = {W0f, W1f, 1.f, W1f, W0f, 0.f};
        constexpr float wBr[6] = {0.f, W0f, W1f, 1.f, W1f, W0f};
        #pragma unroll
        for (int r = 0; r < 6; r++) {
            float U[12];
            U32H2 cl, cr;
            cl.u = uLw[r]; cr.u = uRw[r];
            U[0] = (float)cl.h[0]; U[1] = (float)cl.h[1];
            #pragma unroll
            for (int c = 0; c < 8; c++) U[c + 2] = (float)uM[r].h[c];
            U[10] = (float)cr.h[0]; U[11] = (float)cr.h[1];
            #pragma unroll
            for (int c = 0; c < 12; c++) {
                if (r == 0)             vsA[c] = wAr[0] * U[c];
                else if (wAr[r] != 0.f) vsA[c] += wAr[r] * U[c];
                if (r == 1)             vsB[c] = wBr[1] * U[c];
                else if (wBr[r] != 0.f) vsB[c] += wBr[r] * U[c];
            }
            if (r >= 1 && r <= 4) {
                #pragma unroll
                for (int c = 0; c < 10; c++) Ue[r - 1][c] = U[c + 1];
            }
        }

        const float dxA = xA - cxf;
        const float dxB = xB - cxf;
        const float dxu = (float)ia - cxf;

        float blA = 0.f, blB = 0.f;
        {
            const float dyl = (float)jb - cyf;
            float ad, bl, qd;
            evalF(Ue[1][0], Ue[2][0], Ue[1][1], (float)qlAh,
                  dxA, dyl, cossin, bsin, asin_, ad, bl, qd);
            if (lok) blA = bl;
            evalF(Ue[2][0], Ue[3][0], Ue[2][1], (float)qlBh,
                  dxB, dyl, cossin, bsin, asin_, ad, bl, qd);
            if (lok) blB = bl;
        }

        // ---- fused k-loop ----
        half8v uhA, uhB, qhA, qhB;
        float s0A = 0.f, syA = 0.f, syyA = 0.f, s0B = 0.f, syB = 0.f, syyB = 0.f;
        float bA_prev = blA, bB_prev = blB;
        #pragma unroll
        for (int k = 0; k < 8; k++) {
            const float Rj = edge1d(jb + k);
            const float cA = W0f * (vsA[k] + vsA[k + 4]) + W1f * (vsA[k + 1] + vsA[k + 3]) + vsA[k + 2];
            const float cB = W0f * (vsB[k] + vsB[k + 4]) + W1f * (vsB[k + 1] + vsB[k + 3]) + vsB[k + 2];
            const float p4A = INV_NORM * (RiA * Rj - 2.0f * cA);
            const float p4B = INV_NORM * (RiB * Rj - 2.0f * cB);

            const float dy = (float)(jb + k + 1) - cyf;
            float aA, bA, qnA;
            evalF(Ue[1][k + 1], Ue[2][k + 1], Ue[1][k + 2], (float)qcA.h[k],
                  dxA, dy, cossin, bsin, asin_, aA, bA, qnA);
            float au, bu_d, qu_d;
            evalF(Ue[0][k + 1], Ue[1][k + 1], Ue[0][k + 2], (float)qu.h[k],
                  dxu, dy, cossin, bsin, asin_, au, bu_d, qu_d);
            const float aUA = (ia > 0) ? au : 0.f;
            float aB, bB, qnB;
            evalF(Ue[2][k + 1], Ue[3][k + 1], Ue[2][k + 2], (float)qcB.h[k],
                  dxB, dy, cossin, bsin, asin_, aB, bB, qnB);

            const float TqA = aA + bA - aUA - bA_prev;
            const float TqB = aB + bB - aA - bB_prev;
            const float tAv = (float)oA8[k] - p4A - TqA;
            const float tBv = (float)oB8[k] - p4B - TqB;

            uhA[k] = (h16)fast_sigmoid(tAv);
            uhB[k] = (h16)fast_sigmoid(tBv);
            qhA[k] = (h16)qnA;
            qhB[k] = (h16)qnB;

            const float urA = (float)uhA[k];
            const float urB = (float)uhB[k];
            const float y = (float)(jb + k + 1);
            s0A += urA; syA += urA * y; syyA += urA * y * y;
            s0B += urB; syB += urB * y; syyB += urB * y * y;

            if (m == ITER - 1) {
                out[goffA + k] = tAv;
                out[goffB + k] = tBv;
            }
            bA_prev = bA; bB_prev = bB;
        }

        if (m == ITER - 1) return;

        // ---- publish state (agent), drain, then tag partials ----
        {
            H8U su, sq;
            su.h = uhA; ast64(ub + goffA, su.u[0]); ast64(ub + goffA + 4, su.u[1]);
            su.h = uhB; ast64(ub + goffB, su.u[0]); ast64(ub + goffB + 4, su.u[1]);
            sq.h = qhA; ast64(qb + goffA, sq.u[0]); ast64(qb + goffA + 4, sq.u[1]);
            sq.h = qhB; ast64(qb + goffB, sq.u[0]); ast64(qb + goffB + 4, sq.u[1]);
        }
        asm volatile("s_waitcnt vmcnt(0)" ::: "memory");

        float v[6] = {s0A + s0B, xA * s0A + xB * s0B, syA + syB,
                      xA * syA + xB * syB, xA * xA * s0A + xB * xB * s0B, syyA + syyB};
        float* dst = parts + (size_t)(m & 1) * PART_PAR_STRIDE
                           + ((size_t)b * BLK_PER_BATCH + tile) * SLOTF;
        reduce6_store_tagged(v, dst, (float)(m + 2));
    }
}

extern "C" void kernel_launch(void* const* d_in, const int* in_sizes, int n_in,
                              void* d_out, int out_size, void* d_ws, size_t ws_size,
                              hipStream_t stream) {
    const float* o = (const float*)d_in[0];
    float* out = (float*)d_out;

    h16* u0 = (h16*)d_ws;
    h16* u1 = u0 + (size_t)NTOT;
    h16* q0 = u1 + (size_t)NTOT;
    h16* q1 = q0 + (size_t)NTOT;
    h16* oh = q1 + (size_t)NTOT;
    float* parts = (float*)(oh + (size_t)NTOT);     // 2 parity buffers

    init_kernel<<<512, 256, 0, stream>>>(o, u0, q0, oh, parts);

    // NORMAL launch (graph-capturable). R9/R10's cooperative launch was
    // silently dropped under capture -> persist never ran.
    persist_kernel<<<512, 256, 0, stream>>>(oh, u0, u1, q0, q1, parts, out);
}

// Round 16
// 516.065 us; speedup vs baseline: 1.8622x; 1.8622x over previous
//
#include <hip/hip_runtime.h>
#include <math.h>

typedef _Float16 h16;
typedef h16 half8v __attribute__((ext_vector_type(8)));
typedef h16 half4v __attribute__((ext_vector_type(4)));
typedef h16 half2v __attribute__((ext_vector_type(2)));

#define HH 512
#define WW 512
#define BB 8
#define NPIX (HH*WW)        // 262144
#define NTOT (BB*NPIX)      // 2097152
#define ITER 50

#define TX 64               // tile cols
#define TILE_ROWS 64        // tile rows = 32 ty * 2 rows/thread

#define BLK_PER_BATCH 64
#define PART_ITER_STRIDE (BB*BLK_PER_BATCH*8)   // 4096 floats per iteration

// Gaussian 5x5 (sigma=5)
constexpr double W0d = 0.92311634638663587;  // exp(-0.08)
constexpr double W1d = 0.98019867330675525;  // exp(-0.02)
constexpr double SUM1D = 1.0 + 2.0*(W0d + W1d);
constexpr float  INV_NORM = (float)(1.0/(SUM1D*SUM1D + 1e-15));
constexpr float  W0f = (float)W0d;
constexpr float  W1f = (float)W1d;
constexpr float  S1f = (float)SUM1D;

// fast sigmoid: v_exp + v_rcp (1-2 ulp; fp16 state rounding dominates)
__device__ __forceinline__ float fast_sigmoid(float x) {
    const float e = __expf(-x);
    return __builtin_amdgcn_rcpf(1.0f + e);
}

__device__ __forceinline__ float edge1d(int v) {
    float r = S1f;
    if (v == 0 || v == HH - 1) r = S1f - W0f - W1f;
    else if (v == 1 || v == HH - 2) r = S1f - W0f;
    return r;
}

union U32H2 { unsigned u; h16 h[2]; };

// Block-level reduce of 6 floats, one plain store to private partials slot.
// (no atomics, no fences — each block owns its slot; the DISPATCH BOUNDARY
// is the synchronization mechanism. Three in-kernel sync designs (R2 fence,
// R12 all-sc1, R14 perimeter-sc1) were slower or replay-unsafe on 8-XCD.)
__device__ __forceinline__ void reduce6_store(float v[6], float* dst8) {
    #pragma unroll
    for (int kk = 0; kk < 6; kk++) {
        float x = v[kk];
        #pragma unroll
        for (int off = 32; off > 0; off >>= 1) x += __shfl_down(x, off, 64);
        v[kk] = x;
    }
    __shared__ float sm[4][6];
    const int lane = threadIdx.x & 63;
    const int wv   = threadIdx.x >> 6;
    if (lane == 0) {
        #pragma unroll
        for (int kk = 0; kk < 6; kk++) sm[wv][kk] = v[kk];
    }
    __syncthreads();
    if (threadIdx.x == 0) {
        float tt[6];
        #pragma unroll
        for (int kk = 0; kk < 6; kk++) tt[kk] = sm[0][kk] + sm[1][kk] + sm[2][kk] + sm[3][kk];
        *(float4*)dst8       = make_float4(tt[0], tt[1], tt[2], tt[3]);
        *(float4*)(dst8 + 4) = make_float4(tt[4], tt[5], 0.f, 0.f);
    }
}

__device__ __forceinline__ void evalF(float uc, float ud, float ur, float qv,
                                      float dx, float dy,
                                      float cossin, float bsin, float asin_,
                                      float& a, float& bv, float& qn) {
    float Tx = -dx * cossin + dy * bsin;
    float Ty =  dy * cossin - dx * asin_;
    const float rn = __builtin_amdgcn_rsqf(Tx * Tx + Ty * Ty + 1e-20f);
    Tx *= rn; Ty *= rn;
    qn = qv - ((ud - uc) * Tx + (ur - uc) * Ty);
    a  = Tx * qn;
    bv = Ty * qn;
}

// u0 = sigmoid(o) (rounded to fp16); q0 = 0; o -> fp16; partials[0] from rounded u.
// 512 blocks x 256 threads x 16 px (one row segment per thread).
__global__ __launch_bounds__(256) void init_kernel(const float* __restrict__ o,
                                                   h16* __restrict__ u,
                                                   h16* __restrict__ q,
                                                   h16* __restrict__ oh,
                                                   float* __restrict__ part0) {
    const int b     = blockIdx.x & 7;
    const int chunk = blockIdx.x >> 3;                  // 0..63
    const int within = chunk * 4096 + threadIdx.x * 16; // 16 consecutive px, row-aligned
    const int pix = b * NPIX + within;
    const int i = within >> 9;
    const int j = within & (WW - 1);

    float of[16];
    #pragma unroll
    for (int s = 0; s < 4; s++) {
        const float4 ov = *(const float4*)(o + pix + 4 * s);
        of[4*s+0] = ov.x; of[4*s+1] = ov.y; of[4*s+2] = ov.z; of[4*s+3] = ov.w;
    }

    half8v oh8[2], uh8[2], qz8[2];
    float urf[16];
    #pragma unroll
    for (int kk = 0; kk < 16; kk++) {
        oh8[kk >> 3][kk & 7] = (h16)of[kk];
        uh8[kk >> 3][kk & 7] = (h16)fast_sigmoid(of[kk]);
        urf[kk] = (float)uh8[kk >> 3][kk & 7];
        qz8[kk >> 3][kk & 7] = (h16)0.f;
    }
    *(half8v*)(u + pix)      = uh8[0];
    *(half8v*)(u + pix + 8)  = uh8[1];
    *(half8v*)(q + pix)      = qz8[0];
    *(half8v*)(q + pix + 8)  = qz8[1];
    *(half8v*)(oh + pix)     = oh8[0];
    *(half8v*)(oh + pix + 8) = oh8[1];

    const float x = (float)(i + 1);
    float s0 = 0.f, sy = 0.f, syy = 0.f;
    #pragma unroll
    for (int kk = 0; kk < 16; kk++) {
        const float y = (float)(j + 1 + kk);
        s0 += urf[kk]; sy += urf[kk] * y; syy += urf[kk] * y * y;
    }
    float v[6] = {s0, x * s0, sy, x * sy, x * x * s0, syy};
    reduce6_store(v, part0 + ((size_t)b * BLK_PER_BATCH + chunk) * 8);
}

// One fused iteration, fp16 state. Each thread computes a 2x8 pixel block.
// Window halos (2 cols each side) come from the NEIGHBOR LANE via __shfl
// instead of global loads (bit-identical values, different transport):
// lane tx's uL = lane tx-1's uM halves 6..7; uR = lane tx+1's uM halves 0..1.
// Only tile-edge lanes (tx==0 / tx==7) load halos from global (exec-masked).
__global__ __launch_bounds__(256) void step_kernel(const h16* __restrict__ oh,
                                                   const h16* __restrict__ uA,
                                                   const h16* __restrict__ qA,
                                                   h16* __restrict__ uB,
                                                   h16* __restrict__ qB,
                                                   const float* __restrict__ partIn,
                                                   float* __restrict__ partOut,
                                                   float* __restrict__ out,
                                                   int lastFlag) {
    const int b    = blockIdx.x & 7;           // batch -> L2 locality
    const int tile = blockIdx.x >> 3;          // 0..63
    const int j0 = (tile & 7) * TX;
    const int i0 = (tile >> 3) * TILE_ROWS;    // 0..448 step 64
    const h16* ubase = uA + (size_t)b * NPIX;
    const h16* qbase = qA + (size_t)b * NPIX;

    const int lin  = threadIdx.x;
    const int lane = lin & 63;
    const int tx = lin & 7;
    const int ty = lin >> 3;                   // 0..31
    const int ia = i0 + 2 * ty;                // row A (even)
    const int jb = j0 + 8 * tx;
    const int loffA = ia * WW + jb;
    const int loffB = loffA + WW;
    const size_t goffA = (size_t)b * NPIX + loffA;
    const size_t goffB = goffA + WW;

    const bool lok = (jb > 0);
    const bool rok = (jb + 8 < WW);
    const bool ltx = (tx > 0);                 // left neighbor lane exists
    const bool rtx = (tx < 7);                 // right neighbor lane exists

    // ======== entry: issue ALL global loads ========
    // partials: 64 slots/batch, exactly one per lane
    const float* P0 = partIn + (size_t)b * (BLK_PER_BATCH * 8) + lane * 8;
    const float4 pA0 = *(const float4*)P0;
    const float4 pB0 = *(const float4*)(P0 + 4);

    // u window: rows ia-2..ia+3. Interior cols via one aligned half8; halo
    // u32s only loaded by tile-edge lanes (2/8 of lanes, exec-masked).
    half8v uM[6];
    unsigned uLbw[6], uRbw[6];
    #pragma unroll
    for (int r = 0; r < 6; r++) {
        const int ii = ia - 2 + r;
        const bool rowok = (ii >= 0 && ii < HH);
        half8v m;
        #pragma unroll
        for (int c = 0; c < 8; c++) m[c] = (h16)0.f;
        unsigned lw = 0u, rw = 0u;
        if (rowok) {
            const h16* rowp = ubase + ii * WW;
            m = *(const half8v*)(rowp + jb);
            if (!ltx && lok) lw = *(const unsigned*)(rowp + jb - 2);
            if (!rtx && rok) rw = *(const unsigned*)(rowp + jb + 8);
        }
        uM[r] = m; uLbw[r] = lw; uRbw[r] = rw;
    }
    // q rows A, B, up(A-1); o rows A, B. q-left via shfl (boundary lanes load).
    const half8v qcA8 = *(const half8v*)(qbase + loffA);
    const half8v qcB8 = *(const half8v*)(qbase + loffB);
    const half8v qu8  = *(const half8v*)(qbase + ((ia > 0) ? loffA - WW : loffA));
    h16 qlA_g = (h16)0.f, qlB_g = (h16)0.f;
    if (!ltx && lok) {
        qlA_g = qbase[loffA - 1];
        qlB_g = qbase[loffB - 1];
    }
    const half8v oA8  = *(const half8v*)(oh + goffA);
    const half8v oB8  = *(const half8v*)(oh + goffB);

    // ======== per-wave scalar finalize (butterfly, no LDS / no barrier) ========
    float v6[6] = {pA0.x, pA0.y, pA0.z, pA0.w, pB0.x, pB0.y};
    #pragma unroll
    for (int mask = 1; mask < 64; mask <<= 1) {
        #pragma unroll
        for (int c = 0; c < 6; c++) v6[c] += __shfl_xor(v6[c], mask, 64);
    }
    const double sS  = (double)v6[0];
    const double inv = 1.0 / sS;
    const double cxd = (double)v6[1] * inv;
    const double cyd = (double)v6[2] * inv;
    const float cxf    = (float)cxd;
    const float cyf    = (float)cyd;
    const float cossin = (float)((double)v6[3] * inv - cxd * cyd);
    const float bsin   = (float)((double)v6[4] * inv - cxd * cxd);
    const float asin_  = (float)((double)v6[5] * inv - cyd * cyd);

    // ======== derive halos from neighbor lanes (wave-level sharing) ========
    unsigned uLw[6], uRw[6];
    #pragma unroll
    for (int r = 0; r < 6; r++) {
        const unsigned w3 = ((const unsigned*)&uM[r])[3];   // halves 6,7
        const unsigned w0 = ((const unsigned*)&uM[r])[0];   // halves 0,1
        const unsigned fromL = (unsigned)__shfl((int)w3, lane - 1, 64);
        const unsigned fromR = (unsigned)__shfl((int)w0, lane + 1, 64);
        uLw[r] = ltx ? fromL : uLbw[r];
        uRw[r] = rtx ? fromR : uRbw[r];
    }
    h16 qlAh, qlBh;
    {
        const unsigned qa3 = ((const unsigned*)&qcA8)[3];
        const unsigned qb3 = ((const unsigned*)&qcB8)[3];
        U32H2 ca, cb;
        ca.u = (unsigned)__shfl((int)qa3, lane - 1, 64);
        cb.u = (unsigned)__shfl((int)qb3, lane - 1, 64);
        qlAh = ltx ? ca.h[1] : qlA_g;      // neighbor's col jb-1 (half index 7)
        qlBh = ltx ? cb.h[1] : qlB_g;
    }

    // ======== streaming v-pass over 6 window rows; keep rows 1..4 cols 1..10 ========
    float vsA[12], vsB[12];
    float Ue[4][10];           // window rows 1..4 (up,A,B,below), cols 1..10
    constexpr float wAr[6] = {W0f, W1f, 1.f, W1f, W0f, 0.f};
    constexpr float wBr[6] = {0.f, W0f, W1f, 1.f, W1f, W0f};
    #pragma unroll
    for (int r = 0; r < 6; r++) {
        float U[12];
        U32H2 cl, cr;
        cl.u = uLw[r]; cr.u = uRw[r];
        U[0] = (float)cl.h[0]; U[1] = (float)cl.h[1];
        #pragma unroll
        for (int c = 0; c < 8; c++) U[c + 2] = (float)uM[r][c];
        U[10] = (float)cr.h[0]; U[11] = (float)cr.h[1];
        #pragma unroll
        for (int c = 0; c < 12; c++) {
            if (r == 0)             vsA[c] = wAr[0] * U[c];
            else if (wAr[r] != 0.f) vsA[c] += wAr[r] * U[c];
            if (r == 1)             vsB[c] = wBr[1] * U[c];
            else if (wBr[r] != 0.f) vsB[c] += wBr[r] * U[c];
        }
        if (r >= 1 && r <= 4) {
            #pragma unroll
            for (int c = 0; c < 10; c++) Ue[r - 1][c] = U[c + 1];
        }
    }

    const float RiA = edge1d(ia);
    const float RiB = edge1d(ia + 1);
    const float dxA = (float)(ia + 1) - cxf;
    const float dxB = (float)(ia + 2) - cxf;
    const float dxu = (float)ia - cxf;

    // left-boundary evals (col jb-1) for both rows
    float blA = 0.f, blB = 0.f;
    {
        const float dyl = (float)jb - cyf;
        float ad, bl, qd;
        evalF(Ue[1][0], Ue[2][0], Ue[1][1], (float)qlAh,
              dxA, dyl, cossin, bsin, asin_, ad, bl, qd);
        if (lok) blA = bl;
        evalF(Ue[2][0], Ue[3][0], Ue[2][1], (float)qlBh,
              dxB, dyl, cossin, bsin, asin_, ad, bl, qd);
        if (lok) blB = bl;
    }

    // ======== fused k-loop: h-pass + 3 evalF + update per column ========
    half8v uhA, uhB, qhA, qhB;
    float s0A = 0.f, syA = 0.f, syyA = 0.f, s0B = 0.f, syB = 0.f, syyB = 0.f;
    float bA_prev = blA, bB_prev = blB;
    #pragma unroll
    for (int k = 0; k < 8; k++) {
        const float Rj = edge1d(jb + k);
        const float cA = W0f * (vsA[k] + vsA[k + 4]) + W1f * (vsA[k + 1] + vsA[k + 3]) + vsA[k + 2];
        const float cB = W0f * (vsB[k] + vsB[k + 4]) + W1f * (vsB[k + 1] + vsB[k + 3]) + vsB[k + 2];
        const float p4A = INV_NORM * (RiA * Rj - 2.0f * cA);
        const float p4B = INV_NORM * (RiB * Rj - 2.0f * cB);

        const float dy = (float)(jb + k + 1) - cyf;
        float aA, bA, qnA;
        evalF(Ue[1][k + 1], Ue[2][k + 1], Ue[1][k + 2], (float)qcA8[k],
              dxA, dy, cossin, bsin, asin_, aA, bA, qnA);
        float au, bu_d, qu_d;
        evalF(Ue[0][k + 1], Ue[1][k + 1], Ue[0][k + 2], (float)qu8[k],
              dxu, dy, cossin, bsin, asin_, au, bu_d, qu_d);
        const float aUA = (ia > 0) ? au : 0.f;
        float aB, bB, qnB;
        evalF(Ue[2][k + 1], Ue[3][k + 1], Ue[2][k + 2], (float)qcB8[k],
              dxB, dy, cossin, bsin, asin_, aB, bB, qnB);

        const float TqA = aA + bA - aUA - bA_prev;
        const float TqB = aB + bB - aA - bB_prev;    // row B up = row A center
        const float tAv = (float)oA8[k] - p4A - TqA;
        const float tBv = (float)oB8[k] - p4B - TqB;

        uhA[k] = (h16)fast_sigmoid(tAv);
        uhB[k] = (h16)fast_sigmoid(tBv);
        qhA[k] = (h16)qnA;
        qhB[k] = (h16)qnB;

        // sums use the ROUNDED u for field consistency
        const float urA = (float)uhA[k];
        const float urB = (float)uhB[k];
        const float y = (float)(jb + k + 1);
        s0A += urA; syA += urA * y; syyA += urA * y * y;
        s0B += urB; syB += urB * y; syyB += urB * y * y;

        if (lastFlag) {                      // rare path (1 of 50 iterations)
            out[goffA + k] = tAv;
            out[goffB + k] = tBv;
        }
        bA_prev = bA; bB_prev = bB;
    }

    *(half8v*)(uB + goffA) = uhA;
    *(half8v*)(uB + goffB) = uhB;
    *(half8v*)(qB + goffA) = qhA;
    *(half8v*)(qB + goffB) = qhB;
    if (lastFlag) return;                    // no next iteration: partials not needed

    const float xA = (float)(ia + 1);
    const float xB = (float)(ia + 2);
    float v[6] = {s0A + s0B, xA * s0A + xB * s0B, syA + syB,
                  xA * syA + xB * syB, xA * xA * s0A + xB * xB * s0B, syyA + syyB};
    reduce6_store(v, partOut + ((size_t)b * BLK_PER_BATCH + tile) * 8);
}

extern "C" void kernel_launch(void* const* d_in, const int* in_sizes, int n_in,
                              void* d_out, int out_size, void* d_ws, size_t ws_size,
                              hipStream_t stream) {
    const float* o = (const float*)d_in[0];
    float* out = (float*)d_out;

    h16* uA = (h16*)d_ws;
    h16* uB = uA + (size_t)NTOT;
    h16* qA = uB + (size_t)NTOT;
    h16* qB = qA + (size_t)NTOT;
    h16* oh = qB + (size_t)NTOT;
    float* partials = (float*)(oh + (size_t)NTOT);   // 51 iters * 4096 floats

    init_kernel<<<512, 256, 0, stream>>>(o, uA, qA, oh, partials);

    h16 *ua = uA, *ub = uB, *qa = qA, *qb = qB;
    for (int k = 0; k < ITER; k++) {
        step_kernel<<<512, 256, 0, stream>>>(
            oh, ua, qa, ub, qb,
            partials + (size_t)k * PART_ITER_STRIDE,
            partials + (size_t)(k + 1) * PART_ITER_STRIDE,
            out, (k == ITER - 1) ? 1 : 0);
        h16* tmp;
        tmp = ua; ua = ub; ub = tmp;
        tmp = qa; qa = qb; qb = tmp;
    }
}